// Round 10
// baseline (15.807 us; speedup 1.0000x reference)
//
#include <hip/hip_runtime.h>

#define F 26
#define A 7
#define DIM 16
#define BATCH 4096
#define TV 2083764

__device__ __constant__ int c_OFFSETS[F] = {
    0, 1000000, 1500000, 1750000, 1850000, 1950000, 2000000, 2050000,
    2060000, 2070000, 2075000, 2080000, 2081000, 2082000, 2082500, 2083000,
    2083200, 2083400, 2083500, 2083600, 2083650, 2083700, 2083720, 2083740,
    2083750, 2083760};
__device__ __constant__ int c_FIELD_DIMS[F] = {
    1000000, 500000, 250000, 100000, 100000, 50000, 50000, 10000, 10000,
    5000, 5000, 1000, 1000, 500, 500, 200, 200, 100, 100, 50, 50, 20, 20,
    10, 10, 4};
__device__ __constant__ int c_ACTION[A] = {1, 64, 128, 256, 512, 1024, 2048};

// Block: 256 threads = 4 waves = 2 batch elements (2 waves per element,
// contiguous field split as in round 8: wave h owns fields h*16 .. h*16+15).
// NO front barrier: each wave computes its own 16 gid+probs rows in
// registers (lane s preps field h*16+(s&15)) and distributes them with 8
// shfls. Branchless clamped gathers (dead -> line 0, weight exactly 0).
// One end barrier for the cross-wave combine.
__global__ __launch_bounds__(256, 8) void gsq_fm_kernel(
    const int* __restrict__ x,            // (B, F)
    const float* __restrict__ emb_table,  // (TV, 16)
    const float* __restrict__ lin_w,      // (TV, 1)
    const float* __restrict__ lin_bias,   // (1,)
    const float* __restrict__ codebooks,  // (6, F, 2048, 16)
    const int* __restrict__ assignments,  // (6, TV)
    const float* __restrict__ arch,       // (F, A)
    const float* __restrict__ gumbel,     // (F, A)
    float* __restrict__ out)              // (B,)
{
    __shared__ float4 s_red[2][2][4];   // [e][h][dh]
    __shared__ float q_red[2][2];
    __shared__ float lin_red[2][2];

    const int t = threadIdx.x;
    const int lane = t & 63;
    const int h = (t >> 6) & 1;    // wave within pair
    const int e = t >> 7;          // batch sub-index (0..1)
    const int b = blockIdx.x * 2 + e;
    const int sub = lane >> 2;     // field sub-group 0..15
    const int dh = lane & 3;       // dims 4*dh .. 4*dh+3

    // ---- per-wave register prep: lane s preps field h*16 + (s&15) ----
    const int fp = h * 16 + (lane & 15);   // 0..31; >=26 are dead pads
    const bool pv = (fp < F);
    const int fpc = pv ? fp : 0;           // clamped for safe addressing
    const int gid_p = pv ? (x[b * F + fp] + c_OFFSETS[fp]) : 0;

    float p_r[A];
    {
        const int dims = c_FIELD_DIMS[fpc];
        float z[A];
        float m = -1e30f;
#pragma unroll
        for (int k = 0; k < A; ++k) {
            const bool allowed = (k == 0) ? (dims < 150)
                                          : (5 * c_ACTION[k] <= 2 * dims);
            const float logit = allowed ? arch[fpc * A + k] : -1e9f;
            z[k] = logit + gumbel[fpc * A + k];  // TEMPERATURE == 1
            m = fmaxf(m, z[k]);
        }
        float ssum = 0.f;
#pragma unroll
        for (int k = 0; k < A; ++k) {
            z[k] = expf(z[k] - m);  // disallowed -> exactly 0.0f
            ssum += z[k];
        }
        const float inv = pv ? (1.f / ssum) : 0.f;  // pads -> all-zero probs
#pragma unroll
        for (int k = 0; k < A; ++k) p_r[k] = z[k] * inv;
    }

    // ---- distribute to consumers: my field f = h*16 + sub (lane 'sub' prepped it) ----
    const int f = h * 16 + sub;
    const bool valid = (f < F);
    const int gid = __shfl(gid_p, sub, 64);
    float w[A];
#pragma unroll
    for (int k = 0; k < A; ++k) w[k] = __shfl(p_r[k], sub, 64);

    // ---- emb path (clamped: dead -> line 0, weight exactly 0) ----
    const float p0 = w[0];
    const int eoff = (p0 != 0.f) ? gid * DIM : 0;
    const float4 er = *(const float4*)&emb_table[eoff + 4 * dh];
    float xx = p0 * er.x, xy = p0 * er.y, xz = p0 * er.z, xw = p0 * er.w;

    // ---- code gathers: unconditional, clamped, all independent ----
    int coff[6];
#pragma unroll
    for (int a = 0; a < 6; ++a) {
        const bool live = (w[a + 1] != 0.f);
        const int aaddr = live ? (a * TV + gid) : 0;
        const int code = assignments[aaddr];
        coff[a] = live ? (((a * F + f) * 2048 + code) * DIM) : 0;
    }
    // ---- row gathers + accumulate ----
#pragma unroll
    for (int a = 0; a < 6; ++a) {
        const float4 r = *(const float4*)&codebooks[coff[a] + 4 * dh];
        xx = fmaf(w[a + 1], r.x, xx);
        xy = fmaf(w[a + 1], r.y, xy);
        xz = fmaf(w[a + 1], r.z, xz);
        xw = fmaf(w[a + 1], r.w, xw);
    }

    float q = xx * xx + xy * xy + xz * xz + xw * xw;

    // lin: branchless masked
    const float lm = (dh == 0 && valid) ? 1.f : 0.f;
    const float lv = lin_w[valid ? gid : 0];
    float lin = lm * lv;

    // ---- in-wave reductions ----
    float sx = xx, sy = xy, sz = xz, sw = xw;
    // s: sum across the 16 sub-groups (lane bits 2..5)
    sx += __shfl_xor(sx, 4, 64);  sx += __shfl_xor(sx, 8, 64);
    sx += __shfl_xor(sx, 16, 64); sx += __shfl_xor(sx, 32, 64);
    sy += __shfl_xor(sy, 4, 64);  sy += __shfl_xor(sy, 8, 64);
    sy += __shfl_xor(sy, 16, 64); sy += __shfl_xor(sy, 32, 64);
    sz += __shfl_xor(sz, 4, 64);  sz += __shfl_xor(sz, 8, 64);
    sz += __shfl_xor(sz, 16, 64); sz += __shfl_xor(sz, 32, 64);
    sw += __shfl_xor(sw, 4, 64);  sw += __shfl_xor(sw, 8, 64);
    sw += __shfl_xor(sw, 16, 64); sw += __shfl_xor(sw, 32, 64);

    // q, lin: full 64-lane butterflies
    q += __shfl_xor(q, 1, 64);  q += __shfl_xor(q, 2, 64);
    q += __shfl_xor(q, 4, 64);  q += __shfl_xor(q, 8, 64);
    q += __shfl_xor(q, 16, 64); q += __shfl_xor(q, 32, 64);
    lin += __shfl_xor(lin, 1, 64);  lin += __shfl_xor(lin, 2, 64);
    lin += __shfl_xor(lin, 4, 64);  lin += __shfl_xor(lin, 8, 64);
    lin += __shfl_xor(lin, 16, 64); lin += __shfl_xor(lin, 32, 64);

    if (lane < 4) {
        s_red[e][h][lane] = make_float4(sx, sy, sz, sw);
    }
    if (lane == 0) {
        q_red[e][h] = q;
        lin_red[e][h] = lin;
    }
    __syncthreads();

    // ---- cross-wave combine (wave h==0 of each pair) ----
    if (h == 0) {
        const float4 a0 = s_red[e][0][dh];
        const float4 a1 = s_red[e][1][dh];
        const float tx = a0.x + a1.x, ty = a0.y + a1.y;
        const float tz = a0.z + a1.z, tw = a0.w + a1.w;
        float val = tx * tx + ty * ty + tz * tz + tw * tw;  // per-dh partial
        val += __shfl_xor(val, 1, 64);
        val += __shfl_xor(val, 2, 64);
        if (lane == 0) {
            const float qt = q_red[e][0] + q_red[e][1];
            const float lt = lin_red[e][0] + lin_red[e][1];
            out[b] = lt + lin_bias[0] + 0.5f * (val - qt);
        }
    }
}

extern "C" void kernel_launch(void* const* d_in, const int* in_sizes, int n_in,
                              void* d_out, int out_size, void* d_ws, size_t ws_size,
                              hipStream_t stream) {
    const int*   x           = (const int*)d_in[0];
    const float* emb_table   = (const float*)d_in[1];
    const float* lin_w       = (const float*)d_in[2];
    const float* lin_bias    = (const float*)d_in[3];
    const float* codebooks   = (const float*)d_in[4];
    const int*   assignments = (const int*)d_in[5];
    const float* arch        = (const float*)d_in[6];
    const float* gumbel      = (const float*)d_in[7];
    float* out = (float*)d_out;

    dim3 grid(BATCH / 2);   // 2 batch elements (2 waves each) per block
    dim3 block(256);
    hipLaunchKernelGGL(gsq_fm_kernel, grid, block, 0, stream,
                       x, emb_table, lin_w, lin_bias, codebooks, assignments,
                       arch, gumbel, out);
}

// Round 11
// 13.729 us; speedup vs baseline: 1.1514x; 1.1514x over previous
//
#include <hip/hip_runtime.h>

#define F 26
#define FPAD 32
#define A 7
#define DIM 16
#define BATCH 4096
#define TV 2083764

__device__ __constant__ int c_OFFSETS[F] = {
    0, 1000000, 1500000, 1750000, 1850000, 1950000, 2000000, 2050000,
    2060000, 2070000, 2075000, 2080000, 2081000, 2082000, 2082500, 2083000,
    2083200, 2083400, 2083500, 2083600, 2083650, 2083700, 2083720, 2083740,
    2083750, 2083760};
__device__ __constant__ int c_FIELD_DIMS[F] = {
    1000000, 500000, 250000, 100000, 100000, 50000, 50000, 10000, 10000,
    5000, 5000, 1000, 1000, 500, 500, 200, 200, 100, 100, 50, 50, 20, 20,
    10, 10, 4};
__device__ __constant__ int c_ACTION[A] = {1, 64, 128, 256, 512, 1024, 2048};

// Block: 256 threads = 4 waves = 2 batch elements (2 waves per element).
// Wave h of a pair handles fields f = h*16 + sub, sub = lane>>2 (0..15);
// dh = lane&3 covers dims 4*dh..4*dh+3 (float4). Branchless clamped loads
// (dead -> line 0, weight exactly 0). This is the round-8 structure (best
// measured: 13.57 us) — R9 parity split and R10 barrier-free prep both
// regressed; the limiter is random-line service, not schedule.
__global__ __launch_bounds__(256, 8) void gsq_fm_kernel(
    const int* __restrict__ x,            // (B, F)
    const float* __restrict__ emb_table,  // (TV, 16)
    const float* __restrict__ lin_w,      // (TV, 1)
    const float* __restrict__ lin_bias,   // (1,)
    const float* __restrict__ codebooks,  // (6, F, 2048, 16)
    const int* __restrict__ assignments,  // (6, TV)
    const float* __restrict__ arch,       // (F, A)
    const float* __restrict__ gumbel,     // (F, A)
    float* __restrict__ out)              // (B,)
{
    __shared__ float probs_s[FPAD][A];
    __shared__ int gid_s[2][FPAD];
    __shared__ float4 s_red[2][2][4];   // [e][h][dh]
    __shared__ float q_red[2][2];
    __shared__ float lin_red[2][2];

    const int t = threadIdx.x;

    // ---- stage gids for the block's 2 batch elements (threads 0..63) ----
    if (t < 64) {
        const int e = t >> 5;
        const int fi = t & 31;
        gid_s[e][fi] = (fi < F)
            ? (x[(blockIdx.x * 2 + e) * F + fi] + c_OFFSETS[fi])
            : 0;
    }

    // ---- per-block probs (threads 64..95; pad rows zero) ----
    if (t >= 64 && t < 64 + FPAD) {
        const int f = t - 64;
        if (f < F) {
            const int dims = c_FIELD_DIMS[f];
            float z[A];
            float m = -1e30f;
            for (int k = 0; k < A; ++k) {
                bool allowed = (k == 0) ? (dims < 150)
                                        : (5 * c_ACTION[k] <= 2 * dims);
                float logit = allowed ? arch[f * A + k] : -1e9f;
                z[k] = logit + gumbel[f * A + k];  // TEMPERATURE == 1
                m = fmaxf(m, z[k]);
            }
            float ssum = 0.f;
            for (int k = 0; k < A; ++k) {
                z[k] = expf(z[k] - m);  // disallowed -> exactly 0.0f
                ssum += z[k];
            }
            const float inv = 1.f / ssum;
            for (int k = 0; k < A; ++k) probs_s[f][k] = z[k] * inv;
        } else {
            for (int k = 0; k < A; ++k) probs_s[f][k] = 0.f;
        }
    }
    __syncthreads();

    const int lane = t & 63;
    const int h = (t >> 6) & 1;    // wave within pair
    const int e = t >> 7;          // batch sub-index (0..1)
    const int b = blockIdx.x * 2 + e;
    const int sub = lane >> 2;     // field sub-group 0..15
    const int dh = lane & 3;       // dims 4*dh .. 4*dh+3

    const int f = h * 16 + sub;    // 0..31 (26..31 dead pads in wave h=1)
    const int gid = gid_s[e][f];
    const bool valid = (f < F);

    // ---- emb path (clamped: dead -> line 0, weight exactly 0) ----
    const float p0 = probs_s[f][0];
    const int eoff = (p0 != 0.f) ? gid * DIM : 0;
    const float4 er = *(const float4*)&emb_table[eoff + 4 * dh];
    float xx = p0 * er.x, xy = p0 * er.y, xz = p0 * er.z, xw = p0 * er.w;

    // ---- code gathers: unconditional, clamped, all independent ----
    float wgt[6];
    int coff[6];
#pragma unroll
    for (int a = 0; a < 6; ++a) {
        wgt[a] = probs_s[f][a + 1];          // exactly 0 for dead (f,a)
        const bool live = (wgt[a] != 0.f);
        const int aaddr = live ? (a * TV + gid) : 0;
        const int code = assignments[aaddr];
        coff[a] = live ? (((a * F + f) * 2048 + code) * DIM) : 0;
    }
    // ---- row gathers + accumulate ----
#pragma unroll
    for (int a = 0; a < 6; ++a) {
        const float4 r = *(const float4*)&codebooks[coff[a] + 4 * dh];
        xx = fmaf(wgt[a], r.x, xx);
        xy = fmaf(wgt[a], r.y, xy);
        xz = fmaf(wgt[a], r.z, xz);
        xw = fmaf(wgt[a], r.w, xw);
    }

    float q = xx * xx + xy * xy + xz * xz + xw * xw;

    // lin: branchless masked
    const float lm = (dh == 0 && valid) ? 1.f : 0.f;
    const float lv = lin_w[valid ? gid : 0];
    float lin = lm * lv;

    // ---- in-wave reductions ----
    float sx = xx, sy = xy, sz = xz, sw = xw;
    // s: sum across the 16 sub-groups (lane bits 2..5)
    sx += __shfl_xor(sx, 4, 64);  sx += __shfl_xor(sx, 8, 64);
    sx += __shfl_xor(sx, 16, 64); sx += __shfl_xor(sx, 32, 64);
    sy += __shfl_xor(sy, 4, 64);  sy += __shfl_xor(sy, 8, 64);
    sy += __shfl_xor(sy, 16, 64); sy += __shfl_xor(sy, 32, 64);
    sz += __shfl_xor(sz, 4, 64);  sz += __shfl_xor(sz, 8, 64);
    sz += __shfl_xor(sz, 16, 64); sz += __shfl_xor(sz, 32, 64);
    sw += __shfl_xor(sw, 4, 64);  sw += __shfl_xor(sw, 8, 64);
    sw += __shfl_xor(sw, 16, 64); sw += __shfl_xor(sw, 32, 64);

    // q, lin: full 64-lane butterflies
    q += __shfl_xor(q, 1, 64);  q += __shfl_xor(q, 2, 64);
    q += __shfl_xor(q, 4, 64);  q += __shfl_xor(q, 8, 64);
    q += __shfl_xor(q, 16, 64); q += __shfl_xor(q, 32, 64);
    lin += __shfl_xor(lin, 1, 64);  lin += __shfl_xor(lin, 2, 64);
    lin += __shfl_xor(lin, 4, 64);  lin += __shfl_xor(lin, 8, 64);
    lin += __shfl_xor(lin, 16, 64); lin += __shfl_xor(lin, 32, 64);

    if (lane < 4) {
        s_red[e][h][lane] = make_float4(sx, sy, sz, sw);
    }
    if (lane == 0) {
        q_red[e][h] = q;
        lin_red[e][h] = lin;
    }
    __syncthreads();

    // ---- cross-wave combine (wave h==0 of each pair) ----
    if (h == 0) {
        const float4 a0 = s_red[e][0][dh];
        const float4 a1 = s_red[e][1][dh];
        const float tx = a0.x + a1.x, ty = a0.y + a1.y;
        const float tz = a0.z + a1.z, tw = a0.w + a1.w;
        float val = tx * tx + ty * ty + tz * tz + tw * tw;  // per-dh partial
        val += __shfl_xor(val, 1, 64);
        val += __shfl_xor(val, 2, 64);
        if (lane == 0) {
            const float qt = q_red[e][0] + q_red[e][1];
            const float lt = lin_red[e][0] + lin_red[e][1];
            out[b] = lt + lin_bias[0] + 0.5f * (val - qt);
        }
    }
}

extern "C" void kernel_launch(void* const* d_in, const int* in_sizes, int n_in,
                              void* d_out, int out_size, void* d_ws, size_t ws_size,
                              hipStream_t stream) {
    const int*   x           = (const int*)d_in[0];
    const float* emb_table   = (const float*)d_in[1];
    const float* lin_w       = (const float*)d_in[2];
    const float* lin_bias    = (const float*)d_in[3];
    const float* codebooks   = (const float*)d_in[4];
    const int*   assignments = (const int*)d_in[5];
    const float* arch        = (const float*)d_in[6];
    const float* gumbel      = (const float*)d_in[7];
    float* out = (float*)d_out;

    dim3 grid(BATCH / 2);   // 2 batch elements (2 waves each) per block
    dim3 block(256);
    hipLaunchKernelGGL(gsq_fm_kernel, grid, block, 0, stream,
                       x, emb_table, lin_w, lin_bias, codebooks, assignments,
                       arch, gumbel, out);
}